// Round 4
// baseline (274.095 us; speedup 1.0000x reference)
//
#include <hip/hip_runtime.h>
#include <hip/hip_bf16.h>

typedef __bf16 bf16;
typedef __attribute__((ext_vector_type(8)))  __bf16 bf16x8;
typedef __attribute__((ext_vector_type(16))) float  f32x16;

#define B_   512
#define NC_  512
#define K_   4
#define S_   8
#define H_   128
#define D_   64
#define XROW (NC_ * K_)

#define SEGS 2
#define ITEMS_PER_BLOCK (B_ / SEGS)   // 256
#define NITER 16                      // 256 items / (2 pairs * 8 items/iter)

// pi: swap bits 2,3 of within-32 index. Hidden dims stored physically permuted
// so the 32x32 MFMA C/D register layout of layer k IS the B-frag of layer k+1.
static __device__ __forceinline__ int swap23(int v) {
    return (v & ~12) | ((v & 4) << 1) | ((v & 8) >> 1);
}

__global__ __launch_bounds__(256, 2)
void jt_mlp_kernel(const int*   __restrict__ x,
                   const float* __restrict__ W1g, const float* __restrict__ b1g,
                   const float* __restrict__ W2g, const float* __restrict__ b2g,
                   const float* __restrict__ W3g, const float* __restrict__ b3g,
                   float* __restrict__ out)
{
    // exchange buffers: [buf][pair][half][frag][lane][8 bf16]  (lane-contiguous 16B)
    __shared__ __align__(16) bf16  HX[2][2][2][4][64][8];   // 32 KB
    __shared__ __align__(16) float LX[2][2][64][4];         // 4 KB (h=1 writes, h=0 reads)

    const int tid  = threadIdx.x;
    const int lane = tid & 63;
    const int w    = tid >> 6;      // 0..3
    const int pair = w >> 1;        // 0,1
    const int h    = w & 1;         // H-half owned by this wave
    const int l31  = lane & 31;
    const int lhi  = lane >> 5;
    const int kk   = l31 & 3;       // within-item variable position

    const int n    = blockIdx.x >> 1;   // clique
    const int seg  = blockIdx.x & 1;

    const float* W1p = W1g + (size_t)n * (D_ * H_);
    const float* W2p = W2g + (size_t)n * (H_ * H_);
    const float* W3p = W3g + (size_t)n * (H_ * S_);
    const float* b1p = b1g + n * H_;
    const float* b2p = b2g + n * H_;
    const float* b3p = b3g + n * S_;

    const int p31 = swap23(l31);
    const bf16 one = (bf16)1.0f, zero = (bf16)0.0f;

    // -------- register-resident weight fragments (this wave's H-half) --------
    // 32x32x16 A-layout: lane holds A[m=lane&31][k=(lane>>5)*8+j]
    bf16x8 w1f[2][4];
#pragma unroll
    for (int a = 0; a < 2; ++a) {
        const int pc = 32 * (2 * h + a) + p31;
        const float bb = b1p[pc];
#pragma unroll
        for (int kt = 0; kt < 4; ++kt)
#pragma unroll
            for (int j = 0; j < 8; ++j) {
                const int k = kt * 16 + lhi * 8 + j;
                float v = W1p[k * H_ + pc];
                if (kt == 0) {   // parent-var-0 block carries b1 (root: synthetic state-0)
                    const float vb = (n > 0 ? v : 0.f) + bb;
                    v = lhi ? v : vb;
                }
                w1f[a][kt][j] = (bf16)v;
            }
    }
    bf16x8 w2f[2][8], w2b[2];
#pragma unroll
    for (int a = 0; a < 2; ++a) {
        const int pc = 32 * (2 * h + a) + p31;
#pragma unroll
        for (int kt = 0; kt < 8; ++kt)
#pragma unroll
            for (int j = 0; j < 8; ++j)
                w2f[a][kt][j] = (bf16)W2p[(kt * 16 + lhi * 8 + j) * H_ + pc];
#pragma unroll
        for (int j = 0; j < 8; ++j) w2b[a][j] = zero;
        w2b[a][0] = lhi ? zero : (bf16)b2p[pc];
    }
    // L3 over this wave's k-half: frag t covers k = 64h + 16t + 8lhi + j
    bf16x8 w3f[4];
#pragma unroll
    for (int t = 0; t < 4; ++t)
#pragma unroll
        for (int j = 0; j < 8; ++j)
            w3f[t][j] = (l31 < S_) ? (bf16)W3p[(64 * h + 16 * t + lhi * 8 + j) * S_ + l31]
                                   : zero;
    bf16x8 onef;
#pragma unroll
    for (int j = 0; j < 8; ++j) onef[j] = zero;
    onef[0] = lhi ? zero : one;

    const float4 b3q = *(const float4*)(b3p + 4 * lhi);   // states 4lhi..4lhi+3

    f32x16 zf;
#pragma unroll
    for (int i = 0; i < 16; ++i) zf[i] = 0.f;

    // -------- x prefetch --------
    const int itbase = seg * ITEMS_PER_BLOCK + pair * 128 + (l31 >> 2);
    int4 xo_c, xp_c;
    {
        const int* xb = x + (size_t)itbase * XROW + n * K_;
        xo_c = *(const int4*)xb;
        xp_c = (n > 0) ? *(const int4*)(xb - K_) : make_int4(0, 0, 0, 0);
    }

#pragma unroll 1
    for (int c = 0; c < NITER; ++c) {
        const int buf  = c & 1;
        const int item = itbase + c * 8;
        const int4 xo = xo_c, xp = xp_c;
        if (c < NITER - 1) {
            const int* xb = x + (size_t)(item + 8) * XROW + n * K_;
            xo_c = *(const int4*)xb;
            xp_c = (n > 0) ? *(const int4*)(xb - K_) : make_int4(0, 0, 0, 0);
        }

        // ---- one-hot B-frags from x ----
        int sel[4];
        sel[0] = (n > 0) ? (lhi ? xp.y : xp.x) : (lhi ? -1 : 0);
        sel[1] = (n > 0) ? (lhi ? xp.w : xp.z) : -1;
        sel[2] = (kk > (lhi ? 1 : 0)) ? (lhi ? xo.y : xo.x) : -1;
        sel[3] = (kk > (lhi ? 3 : 2)) ? (lhi ? xo.w : xo.z) : -1;
        bf16x8 bf1[4];
#pragma unroll
        for (int kt = 0; kt < 4; ++kt)
#pragma unroll
            for (int j = 0; j < 8; ++j)
                bf1[kt][j] = (sel[kt] == j) ? one : zero;

        // ---- layer 1 (own H-half) ----
        f32x16 Aa0 = zf, Aa1 = zf;
#pragma unroll
        for (int kt = 0; kt < 4; ++kt) {
            Aa0 = __builtin_amdgcn_mfma_f32_32x32x16_bf16(w1f[0][kt], bf1[kt], Aa0, 0, 0, 0);
            Aa1 = __builtin_amdgcn_mfma_f32_32x32x16_bf16(w1f[1][kt], bf1[kt], Aa1, 0, 0, 0);
        }

        // ---- extract own h1 frags (chained layout), publish to partner ----
        bf16x8 hfo[4];
#pragma unroll
        for (int t = 0; t < 4; ++t) {
            const f32x16& S = (t < 2) ? Aa0 : Aa1;
#pragma unroll
            for (int j = 0; j < 8; ++j)
                hfo[t][j] = (bf16)fmaxf(S[8 * (t & 1) + j], 0.f);
            *(bf16x8*)&HX[buf][pair][h][t][lane][0] = hfo[t];
        }
        __syncthreads();

        // ---- layer 2: own 4 kt-frags + partner's 4 from LDS ----
        f32x16 Cc0 = zf, Cc1 = zf;
#pragma unroll
        for (int t = 0; t < 4; ++t) {
            Cc0 = __builtin_amdgcn_mfma_f32_32x32x16_bf16(w2f[0][4 * h + t], hfo[t], Cc0, 0, 0, 0);
            Cc1 = __builtin_amdgcn_mfma_f32_32x32x16_bf16(w2f[1][4 * h + t], hfo[t], Cc1, 0, 0, 0);
        }
#pragma unroll
        for (int t = 0; t < 4; ++t) {
            bf16x8 hp = *(const bf16x8*)&HX[buf][pair][1 - h][t][lane][0];
            Cc0 = __builtin_amdgcn_mfma_f32_32x32x16_bf16(w2f[0][4 * (1 - h) + t], hp, Cc0, 0, 0, 0);
            Cc1 = __builtin_amdgcn_mfma_f32_32x32x16_bf16(w2f[1][4 * (1 - h) + t], hp, Cc1, 0, 0, 0);
        }
        Cc0 = __builtin_amdgcn_mfma_f32_32x32x16_bf16(w2b[0], onef, Cc0, 0, 0, 0);
        Cc1 = __builtin_amdgcn_mfma_f32_32x32x16_bf16(w2b[1], onef, Cc1, 0, 0, 0);

        // ---- layer 3 partial over own k-half ----
        f32x16 L = zf;
#pragma unroll
        for (int t = 0; t < 4; ++t) {
            bf16x8 hf;
            const f32x16& S = (t < 2) ? Cc0 : Cc1;
#pragma unroll
            for (int j = 0; j < 8; ++j)
                hf[j] = (bf16)fmaxf(S[8 * (t & 1) + j], 0.f);
            L = __builtin_amdgcn_mfma_f32_32x32x16_bf16(w3f[t], hf, L, 0, 0, 0);
        }

        // ---- sum partials across the pair; epilogue on h==0 wave ----
        if (h == 1)
            *(float4*)&LX[buf][pair][lane][0] = make_float4(L[0], L[1], L[2], L[3]);
        __syncthreads();
        if (h == 0) {
            const float4 Lp = *(const float4*)&LX[buf][pair][lane][0];
            float Ls0 = L[0] + Lp.x + b3q.x;
            float Ls1 = L[1] + Lp.y + b3q.y;
            float Ls2 = L[2] + Lp.z + b3q.z;
            float Ls3 = L[3] + Lp.w + b3q.w;

            float m4 = fmaxf(fmaxf(Ls0, Ls1), fmaxf(Ls2, Ls3));
            const float mm = fmaxf(m4, __shfl_xor(m4, 32));
            float e = __expf(Ls0 - mm) + __expf(Ls1 - mm) +
                      __expf(Ls2 - mm) + __expf(Ls3 - mm);
            const float ssum = e + __shfl_xor(e, 32);

            const int xs = (kk & 2) ? ((kk & 1) ? xo.w : xo.z)
                                    : ((kk & 1) ? xo.y : xo.x);
            const float own = (xs & 2) ? ((xs & 1) ? Ls3 : Ls2)
                                       : ((xs & 1) ? Ls1 : Ls0);
            const float oth = __shfl_xor(own, 32);
            const float obs = ((xs >> 2) == lhi) ? own : oth;
            float lp = obs - mm - __logf(ssum);
            lp += __shfl_xor(lp, 1);
            lp += __shfl_xor(lp, 2);
            if (lhi == 0 && kk == 0)
                out[(size_t)item * NC_ + n] = lp;
        }
    }
}

extern "C" void kernel_launch(void* const* d_in, const int* in_sizes, int n_in,
                              void* d_out, int out_size, void* d_ws, size_t ws_size,
                              hipStream_t stream) {
    const int*   x  = (const int*)d_in[0];
    const float* W1 = (const float*)d_in[1];
    const float* b1 = (const float*)d_in[2];
    const float* W2 = (const float*)d_in[3];
    const float* b2 = (const float*)d_in[4];
    const float* W3 = (const float*)d_in[5];
    const float* b3 = (const float*)d_in[6];
    float* out = (float*)d_out;
    jt_mlp_kernel<<<dim3(NC_ * SEGS), 256, 0, stream>>>(x, W1, b1, W2, b2, W3, b3, out);
}

// Round 5
// 181.223 us; speedup vs baseline: 1.5125x; 1.5125x over previous
//
#include <hip/hip_runtime.h>
#include <hip/hip_bf16.h>

typedef __bf16 bf16;
typedef __attribute__((ext_vector_type(8)))  __bf16 bf16x8;
typedef __attribute__((ext_vector_type(16))) float  f32x16;

#define B_   512
#define NC_  512
#define K_   4
#define S_   8
#define H_   128
#define D_   64
#define XROW (NC_ * K_)

#define SEGS 2
#define ITEMS_PER_BLOCK (B_ / SEGS)   // 256
#define NITER 16                      // 256 items / (2 pairs * 8 items/iter)

// pi: swap bits 2,3 of within-32 index. Hidden dims stored physically permuted
// so the 32x32 MFMA C/D register layout of layer k IS the B-frag of layer k+1.
static __device__ __forceinline__ int swap23(int v) {
    return (v & ~12) | ((v & 4) << 1) | ((v & 8) >> 1);
}

__global__ __launch_bounds__(256, 2)
void jt_mlp_kernel(const int*   __restrict__ x,
                   const float* __restrict__ W1g, const float* __restrict__ b1g,
                   const float* __restrict__ W2g, const float* __restrict__ b2g,
                   const float* __restrict__ W3g, const float* __restrict__ b3g,
                   float* __restrict__ out)
{
    // exchange buffers: [buf][pair][half][frag][lane][8 bf16]  (lane-contiguous 16B)
    __shared__ __align__(16) bf16  HX[2][2][2][4][64][8];   // 32 KB
    __shared__ __align__(16) float LX[2][2][64][4];         // 4 KB (h=1 writes, h=0 reads)

    const int tid  = threadIdx.x;
    const int lane = tid & 63;
    const int w    = tid >> 6;      // 0..3
    const int pair = w >> 1;        // 0,1
    const int h    = w & 1;         // H-half owned by this wave
    const int l31  = lane & 31;
    const int lhi  = lane >> 5;
    const int kk   = l31 & 3;       // within-item variable position

    const int n    = blockIdx.x >> 1;   // clique
    const int seg  = blockIdx.x & 1;

    const float* W1p = W1g + (size_t)n * (D_ * H_);
    const float* W2p = W2g + (size_t)n * (H_ * H_);
    const float* W3p = W3g + (size_t)n * (H_ * S_);
    const float* b1p = b1g + n * H_;
    const float* b2p = b2g + n * H_;
    const float* b3p = b3g + n * S_;

    const int p31 = swap23(l31);
    const bf16 one = (bf16)1.0f, zero = (bf16)0.0f;

    // -------- register-resident weight fragments (this wave's H-half) --------
    // NOTE: every register-array subscript below is a compile-time constant
    // after unrolling; runtime `h` appears ONLY in address arithmetic.
    // (r4 used w2f[a][4*h+t] -> runtime index -> whole array demoted to
    // scratch: VGPR_Count=88, WRITE_SIZE=71MB. Do not reintroduce.)
    // 32x32x16 A-layout: lane holds A[m=lane&31][k=(lane>>5)*8+j]
    bf16x8 w1f[2][4];
#pragma unroll
    for (int a = 0; a < 2; ++a) {
        const int pc = 32 * (2 * h + a) + p31;
        const float bb = b1p[pc];
#pragma unroll
        for (int kt = 0; kt < 4; ++kt)
#pragma unroll
            for (int j = 0; j < 8; ++j) {
                const int k = kt * 16 + lhi * 8 + j;
                float v = W1p[k * H_ + pc];
                if (kt == 0) {   // parent-var-0 block carries b1 (root: synthetic state-0)
                    const float vb = (n > 0 ? v : 0.f) + bb;
                    v = lhi ? v : vb;
                }
                w1f[a][kt][j] = (bf16)v;
            }
    }
    // W2 split: own k-quarters (kt = 4h+t) and partner k-quarters (kt = 4(1-h)+t),
    // both indexed by constant t in the main loop.
    bf16x8 w2f_o[2][4], w2f_p[2][4], w2b[2];
#pragma unroll
    for (int a = 0; a < 2; ++a) {
        const int pc = 32 * (2 * h + a) + p31;
#pragma unroll
        for (int t = 0; t < 4; ++t)
#pragma unroll
            for (int j = 0; j < 8; ++j) {
                const int ko = (4 * h + t) * 16 + lhi * 8 + j;
                const int kp = (4 * (1 - h) + t) * 16 + lhi * 8 + j;
                w2f_o[a][t][j] = (bf16)W2p[ko * H_ + pc];
                w2f_p[a][t][j] = (bf16)W2p[kp * H_ + pc];
            }
#pragma unroll
        for (int j = 0; j < 8; ++j) w2b[a][j] = zero;
        w2b[a][0] = lhi ? zero : (bf16)b2p[pc];
    }
    // L3 over this wave's k-half: frag t covers k = 64h + 16t + 8lhi + j
    bf16x8 w3f[4];
#pragma unroll
    for (int t = 0; t < 4; ++t)
#pragma unroll
        for (int j = 0; j < 8; ++j)
            w3f[t][j] = (l31 < S_) ? (bf16)W3p[(64 * h + 16 * t + lhi * 8 + j) * S_ + l31]
                                   : zero;
    bf16x8 onef;
#pragma unroll
    for (int j = 0; j < 8; ++j) onef[j] = zero;
    onef[0] = lhi ? zero : one;

    const float4 b3q = *(const float4*)(b3p + 4 * lhi);   // states 4lhi..4lhi+3

    f32x16 zf;
#pragma unroll
    for (int i = 0; i < 16; ++i) zf[i] = 0.f;

    // -------- x prefetch --------
    const int itbase = seg * ITEMS_PER_BLOCK + pair * 128 + (l31 >> 2);
    int4 xo_c, xp_c;
    {
        const int* xb = x + (size_t)itbase * XROW + n * K_;
        xo_c = *(const int4*)xb;
        xp_c = (n > 0) ? *(const int4*)(xb - K_) : make_int4(0, 0, 0, 0);
    }

#pragma unroll 1
    for (int c = 0; c < NITER; ++c) {
        const int buf  = c & 1;
        const int item = itbase + c * 8;
        const int4 xo = xo_c, xp = xp_c;
        if (c < NITER - 1) {
            const int* xb = x + (size_t)(item + 8) * XROW + n * K_;
            xo_c = *(const int4*)xb;
            xp_c = (n > 0) ? *(const int4*)(xb - K_) : make_int4(0, 0, 0, 0);
        }

        // ---- one-hot B-frags from x ----
        int sel[4];
        sel[0] = (n > 0) ? (lhi ? xp.y : xp.x) : (lhi ? -1 : 0);
        sel[1] = (n > 0) ? (lhi ? xp.w : xp.z) : -1;
        sel[2] = (kk > (lhi ? 1 : 0)) ? (lhi ? xo.y : xo.x) : -1;
        sel[3] = (kk > (lhi ? 3 : 2)) ? (lhi ? xo.w : xo.z) : -1;
        bf16x8 bf1[4];
#pragma unroll
        for (int kt = 0; kt < 4; ++kt)
#pragma unroll
            for (int j = 0; j < 8; ++j)
                bf1[kt][j] = (sel[kt] == j) ? one : zero;

        // ---- layer 1 (own H-half) ----
        f32x16 Aa0 = zf, Aa1 = zf;
#pragma unroll
        for (int kt = 0; kt < 4; ++kt) {
            Aa0 = __builtin_amdgcn_mfma_f32_32x32x16_bf16(w1f[0][kt], bf1[kt], Aa0, 0, 0, 0);
            Aa1 = __builtin_amdgcn_mfma_f32_32x32x16_bf16(w1f[1][kt], bf1[kt], Aa1, 0, 0, 0);
        }

        // ---- extract own h1 frags (chained layout), publish to partner ----
        bf16x8 hfo[4];
#pragma unroll
        for (int t = 0; t < 4; ++t) {
            const f32x16& S = (t < 2) ? Aa0 : Aa1;
#pragma unroll
            for (int j = 0; j < 8; ++j)
                hfo[t][j] = (bf16)fmaxf(S[8 * (t & 1) + j], 0.f);
            *(bf16x8*)&HX[buf][pair][h][t][lane][0] = hfo[t];
        }
        __syncthreads();

        // ---- layer 2: own 4 kt-frags + partner's 4 from LDS (const indices) ----
        f32x16 Cc0 = zf, Cc1 = zf;
#pragma unroll
        for (int t = 0; t < 4; ++t) {
            Cc0 = __builtin_amdgcn_mfma_f32_32x32x16_bf16(w2f_o[0][t], hfo[t], Cc0, 0, 0, 0);
            Cc1 = __builtin_amdgcn_mfma_f32_32x32x16_bf16(w2f_o[1][t], hfo[t], Cc1, 0, 0, 0);
        }
#pragma unroll
        for (int t = 0; t < 4; ++t) {
            bf16x8 hp = *(const bf16x8*)&HX[buf][pair][1 - h][t][lane][0];
            Cc0 = __builtin_amdgcn_mfma_f32_32x32x16_bf16(w2f_p[0][t], hp, Cc0, 0, 0, 0);
            Cc1 = __builtin_amdgcn_mfma_f32_32x32x16_bf16(w2f_p[1][t], hp, Cc1, 0, 0, 0);
        }
        Cc0 = __builtin_amdgcn_mfma_f32_32x32x16_bf16(w2b[0], onef, Cc0, 0, 0, 0);
        Cc1 = __builtin_amdgcn_mfma_f32_32x32x16_bf16(w2b[1], onef, Cc1, 0, 0, 0);

        // ---- layer 3 partial over own k-half ----
        f32x16 L = zf;
#pragma unroll
        for (int t = 0; t < 4; ++t) {
            bf16x8 hf;
            const f32x16& S = (t < 2) ? Cc0 : Cc1;
#pragma unroll
            for (int j = 0; j < 8; ++j)
                hf[j] = (bf16)fmaxf(S[8 * (t & 1) + j], 0.f);
            L = __builtin_amdgcn_mfma_f32_32x32x16_bf16(w3f[t], hf, L, 0, 0, 0);
        }

        // ---- sum partials across the pair; epilogue on h==0 wave ----
        if (h == 1)
            *(float4*)&LX[buf][pair][lane][0] = make_float4(L[0], L[1], L[2], L[3]);
        __syncthreads();
        if (h == 0) {
            const float4 Lp = *(const float4*)&LX[buf][pair][lane][0];
            float Ls0 = L[0] + Lp.x + b3q.x;
            float Ls1 = L[1] + Lp.y + b3q.y;
            float Ls2 = L[2] + Lp.z + b3q.z;
            float Ls3 = L[3] + Lp.w + b3q.w;

            float m4 = fmaxf(fmaxf(Ls0, Ls1), fmaxf(Ls2, Ls3));
            const float mm = fmaxf(m4, __shfl_xor(m4, 32));
            float e = __expf(Ls0 - mm) + __expf(Ls1 - mm) +
                      __expf(Ls2 - mm) + __expf(Ls3 - mm);
            const float ssum = e + __shfl_xor(e, 32);

            const int xs = (kk & 2) ? ((kk & 1) ? xo.w : xo.z)
                                    : ((kk & 1) ? xo.y : xo.x);
            const float own = (xs & 2) ? ((xs & 1) ? Ls3 : Ls2)
                                       : ((xs & 1) ? Ls1 : Ls0);
            const float oth = __shfl_xor(own, 32);
            const float obs = ((xs >> 2) == lhi) ? own : oth;
            float lp = obs - mm - __logf(ssum);
            lp += __shfl_xor(lp, 1);
            lp += __shfl_xor(lp, 2);
            if (lhi == 0 && kk == 0)
                out[(size_t)item * NC_ + n] = lp;
        }
    }
}

extern "C" void kernel_launch(void* const* d_in, const int* in_sizes, int n_in,
                              void* d_out, int out_size, void* d_ws, size_t ws_size,
                              hipStream_t stream) {
    const int*   x  = (const int*)d_in[0];
    const float* W1 = (const float*)d_in[1];
    const float* b1 = (const float*)d_in[2];
    const float* W2 = (const float*)d_in[3];
    const float* b2 = (const float*)d_in[4];
    const float* W3 = (const float*)d_in[5];
    const float* b3 = (const float*)d_in[6];
    float* out = (float*)d_out;
    jt_mlp_kernel<<<dim3(NC_ * SEGS), 256, 0, stream>>>(x, W1, b1, W2, b2, W3, b3, out);
}